// Round 10
// baseline (626.010 us; speedup 1.0000x reference)
//
#include <hip/hip_runtime.h>

#define B_ 64
#define T_ 2048
#define H_ 512
#define A_ 512

typedef unsigned short u16;
typedef __attribute__((ext_vector_type(8))) short bf16x8;
typedef __attribute__((ext_vector_type(4))) float f32x4;

__device__ __forceinline__ unsigned cvtpk(float lo, float hi) {
  unsigned d;
  asm("v_cvt_pk_bf16_f32 %0, %1, %2" : "=v"(d) : "v"(lo), "v"(hi));
  return d;
}

__device__ __forceinline__ float bf2f(u16 h) {
  return __uint_as_float(((unsigned)h) << 16);
}

__device__ __forceinline__ float fast_tanh(float x) {
  // tanh(x) = 1 - 2/(exp2(x*2*log2e)+1); v_exp_f32 is exp2
  float e2;
  asm("v_exp_f32 %0, %1" : "=v"(e2) : "v"(x * 2.8853900817779268f));
  return 1.0f - 2.0f * __builtin_amdgcn_rcpf(e2 + 1.0f);
}

// Barrier that waits ONLY LDS ops: in-flight global loads survive it.
#define BAR_LDS() asm volatile("s_waitcnt lgkmcnt(0)\n\ts_barrier" ::: "memory")

// ---------------- K1: merged W_enc conversion + dec_proj -------------------
// blocks [0,128): W_enc fp32 -> bf16 fragment-tiled
//   unit idx = ks*2048 + (a>>4)*64 + q*16 + (a&15), holds W_enc[a][ks*32+q*8..+8]
// blocks [128,640): dec_proj[b][a] = dot(dec[b,:], W_dec[a,:])
__global__ void k_prep(const float* __restrict__ W, u16* __restrict__ wsB,
                       const float* __restrict__ dec, const float* __restrict__ Wd,
                       float* __restrict__ dp) {
  __shared__ float dl[H_];
  int tid = threadIdx.x;
  int bx = blockIdx.x;
  if (bx < 128) {
    int u = bx * 256 + tid;  // 32768 units
    int a = u >> 6;
    int hq = u & 63;
    int ks = hq >> 2;
    int q = hq & 3;
    const float4* src = (const float4*)(W + a * H_ + hq * 8);
    float4 x0 = src[0], x1 = src[1];
    uint4 pk;
    pk.x = cvtpk(x0.x, x0.y);
    pk.y = cvtpk(x0.z, x0.w);
    pk.z = cvtpk(x1.x, x1.y);
    pk.w = cvtpk(x1.z, x1.w);
    int dst = ks * 2048 + (a >> 4) * 64 + q * 16 + (a & 15);
    ((uint4*)wsB)[dst] = pk;
  } else {
    int e = bx - 128;        // 512 blocks
    int b = e >> 3;
    int a0 = (e & 7) * 64;
    dl[tid] = dec[b * H_ + tid];
    dl[tid + 256] = dec[b * H_ + tid + 256];
    __syncthreads();
    int al = tid >> 2, p = tid & 3;
    const float4* wr = (const float4*)(Wd + (a0 + al) * H_ + p * 128);
    const float4* dv = (const float4*)(dl + p * 128);
    float s = 0.f;
#pragma unroll 8
    for (int i = 0; i < 32; ++i) {
      float4 w4 = wr[i], d4 = dv[i];
      s += w4.x * d4.x + w4.y * d4.y + w4.z * d4.z + w4.w * d4.w;
    }
    s += __shfl_xor(s, 1);
    s += __shfl_xor(s, 2);
    if (p == 0) dp[b * H_ + a0 + al] = s;
  }
}

// ---------------- K2: fused GEMM + tanh + V-dot + local softmax + PV -------
// BM=64, BN=512, 8 waves, launch_bounds(512,4) -> <=128 VGPR, 2 blocks/CU
// (cross-block phase overlap is the latency hider, per R6 vs R7/R9 A/B).
// Chunked (4 K-steps) stage pipeline depth-2; B-frag register rolling
// depth-2 (s0..s3); BAR_LDS (lgkm-only) between chunks keeps global loads
// in flight. Epilogue: distributed butterfly reductions, block-local
// softmax, PV from the LDS tile.
// LDS unit u (16B, 8 bf16) = ks*256 + m*64 + q*16 + r
//   holds enc_bf16[row = m*16+r][cols ks*32+q*8 .. +8]
__launch_bounds__(512, 4)
__global__ void k_scores(const float* __restrict__ enc, const u16* __restrict__ wsB,
                         const float* __restrict__ dpj, const float* __restrict__ V,
                         float* __restrict__ scores, float* __restrict__ part,
                         float* __restrict__ mz) {
  __shared__ __attribute__((aligned(16))) u16 Ab[64 * 512];  // 64 KB
  __shared__ float red[8][64];
  int tid = threadIdx.x;
  int w = tid >> 6, l = tid & 63;
  int q = l >> 4, r = l & 15;
  int m0 = blockIdx.x * 64;
  int b = m0 >> 11;

  // staging decode: thread owns unit it*512+tid (it=0..7); ks = it*2+(tid>>8)
  int rem = tid & 255;
  int sm = rem >> 6, sq = (rem >> 4) & 3, sr = rem & 15;
  const float* ab = enc + (size_t)(m0 + sm * 16 + sr) * H_ + (tid >> 8) * 32 + sq * 8;

  // hoisted epilogue constants
  float vv[4], dd[4];
  const float* db = dpj + b * A_;
#pragma unroll
  for (int n = 0; n < 4; ++n) {
    int col = w * 64 + n * 16 + r;
    vv[n] = V[col];
    dd[n] = db[col];
  }

  const bf16x8* bfrag = (const bf16x8*)wsB;

#define LOADC(P, c)                                                     \
  { P##0 = *((const float4*)(ab + (2 * (c)) * 64));                     \
    P##1 = *((const float4*)(ab + (2 * (c)) * 64 + 4));                 \
    P##2 = *((const float4*)(ab + (2 * (c) + 1) * 64));                 \
    P##3 = *((const float4*)(ab + (2 * (c) + 1) * 64 + 4)); }
#define WRITEC(P, c)                                                    \
  { uint4 k0, k1;                                                       \
    k0.x = cvtpk((P##0).x, (P##0).y); k0.y = cvtpk((P##0).z, (P##0).w); \
    k0.z = cvtpk((P##1).x, (P##1).y); k0.w = cvtpk((P##1).z, (P##1).w); \
    k1.x = cvtpk((P##2).x, (P##2).y); k1.y = cvtpk((P##2).z, (P##2).w); \
    k1.z = cvtpk((P##3).x, (P##3).y); k1.w = cvtpk((P##3).z, (P##3).w); \
    ((uint4*)Ab)[(2 * (c)) * 512 + tid] = k0;                           \
    ((uint4*)Ab)[(2 * (c) + 1) * 512 + tid] = k1; }
#define LOADB(dst, ks)                                                  \
  { _Pragma("unroll") for (int n = 0; n < 4; ++n)                       \
      dst[n] = bfrag[(ks) * 2048 + (w * 4 + n) * 64 + l]; }
#define LOADA(dst, ks)                                                  \
  { _Pragma("unroll") for (int m = 0; m < 4; ++m)                       \
      dst[m] = *((const bf16x8*)&Ab[((ks) * 256 + m * 64 + l) * 8]); }
#define MFMA16(af, bb)                                                  \
  { __builtin_amdgcn_s_setprio(1);                                      \
    _Pragma("unroll") for (int m = 0; m < 4; ++m)                       \
      _Pragma("unroll") for (int n = 0; n < 4; ++n)                     \
        acc[m][n] = __builtin_amdgcn_mfma_f32_16x16x32_bf16(            \
            af[m], bb[n], acc[m][n], 0, 0, 0);                          \
    __builtin_amdgcn_s_setprio(0); }
// chunk c: steps 4c..4c+3 use s0..s3 (each prefetched 2 steps ahead)
#define CHUNK(c, PF3)                                                   \
  { LOADA(aA, 4 * (c));                                                 \
    LOADB(s2, 4 * (c) + 2)                                              \
    LOADA(aB, 4 * (c) + 1);                                             \
    MFMA16(aA, s0)                                                      \
    LOADB(s3, 4 * (c) + 3)                                              \
    LOADA(aA, 4 * (c) + 2);                                             \
    MFMA16(aB, s1)                                                      \
    if (PF3) LOADB(s0, 4 * (c) + 4)                                     \
    LOADA(aB, 4 * (c) + 3);                                             \
    MFMA16(aA, s2)                                                      \
    if (PF3) LOADB(s1, 4 * (c) + 5)                                     \
    MFMA16(aB, s3) }

  f32x4 acc[4][4];
#pragma unroll
  for (int m = 0; m < 4; ++m)
#pragma unroll
    for (int n = 0; n < 4; ++n) acc[m][n] = (f32x4){0.f, 0.f, 0.f, 0.f};

  float4 pa0, pa1, pa2, pa3, pb0, pb1, pb2, pb3;
  bf16x8 s0[4], s1[4], s2[4], s3[4], aA[4], aB[4];

  LOADC(pa, 0)
  LOADC(pb, 1)
  LOADB(s0, 0)
  LOADB(s1, 1)
  WRITEC(pa, 0)
  BAR_LDS();
  LOADC(pa, 2)
  CHUNK(0, true)
  WRITEC(pb, 1)
  BAR_LDS();
  LOADC(pb, 3)
  CHUNK(1, true)
  WRITEC(pa, 2)
  BAR_LDS();
  CHUNK(2, true)
  WRITEC(pb, 3)
  BAR_LDS();
  CHUNK(3, false)

  // ---- scores: sp[i= m*4+j] = sum_n V*tanh(acc+dd), then butterfly ----
  float sp[16];
#pragma unroll
  for (int i = 0; i < 16; ++i) sp[i] = 0.f;
#pragma unroll
  for (int n = 0; n < 4; ++n) {
#pragma unroll
    for (int m = 0; m < 4; ++m)
#pragma unroll
      for (int j = 0; j < 4; ++j)
        sp[m * 4 + j] = fmaf(vv[n], fast_tanh(acc[m][n][j] + dd[n]), sp[m * 4 + j]);
  }
  // distributed reduce over the 16 col-lanes: lane r ends with full sum of
  // sp[bitrev4(r)]
#pragma unroll
  for (int st = 0; st < 4; ++st) {
    const int s = 1 << st;
    const int cnt = 16 >> (st + 1);
    bool hi = (r & s) != 0;
#pragma unroll
    for (int i = 0; i < cnt; ++i) {
      float a = hi ? sp[i + cnt] : sp[i];
      float bs = hi ? sp[i] : sp[i + cnt];
      sp[i] = a + __shfl_xor(bs, s);
    }
  }
  {
    int i4 = ((r & 1) << 3) | ((r & 2) << 1) | ((r & 4) >> 1) | ((r & 8) >> 3);
    BAR_LDS();  // all A-tile LDS reads of K-loop done block-wide
    red[w][(i4 >> 2) * 16 + q * 4 + (i4 & 3)] = sp[0];
  }
  BAR_LDS();

  // ---- ALL waves: final row scores + local softmax ----
  float s_ = 0.f;
#pragma unroll
  for (int ww = 0; ww < 8; ++ww) s_ += red[ww][l];
  if (w == 0) scores[m0 + l] = s_;
  float mx = s_;
#pragma unroll
  for (int off = 1; off <= 32; off <<= 1) mx = fmaxf(mx, __shfl_xor(mx, off));
  float e = __expf(s_ - mx);
  float Z = e;
#pragma unroll
  for (int off = 1; off <= 32; off <<= 1) Z += __shfl_xor(Z, off);
  if (tid == 0) {
    mz[blockIdx.x * 2] = mx;
    mz[blockIdx.x * 2 + 1] = Z;
  }
  float em[4];
#pragma unroll
  for (int m = 0; m < 4; ++m) em[m] = __shfl(e, m * 16 + r);

  // ---- PV: partial ctx[col] = sum_rows e_row * enc_bf16[row][col] ----
  // wave w covers ks = 2w, 2w+1 (cols w*64 .. w*64+64).
  {
    float pv0[8], pv1[8];
#pragma unroll
    for (int j = 0; j < 8; ++j) { pv0[j] = 0.f; pv1[j] = 0.f; }
#pragma unroll
    for (int ksl = 0; ksl < 2; ++ksl) {
      int ks_ = 2 * w + ksl;
#pragma unroll
      for (int m = 0; m < 4; ++m) {
        uint4 pk = ((const uint4*)Ab)[ks_ * 256 + m * 64 + l];
        float er = em[m];
        float v0 = bf2f((u16)(pk.x & 0xffff)), v1 = bf2f((u16)(pk.x >> 16));
        float v2 = bf2f((u16)(pk.y & 0xffff)), v3 = bf2f((u16)(pk.y >> 16));
        float v4 = bf2f((u16)(pk.z & 0xffff)), v5 = bf2f((u16)(pk.z >> 16));
        float v6 = bf2f((u16)(pk.w & 0xffff)), v7 = bf2f((u16)(pk.w >> 16));
        if (ksl == 0) {
          pv0[0] = fmaf(er, v0, pv0[0]); pv0[1] = fmaf(er, v1, pv0[1]);
          pv0[2] = fmaf(er, v2, pv0[2]); pv0[3] = fmaf(er, v3, pv0[3]);
          pv0[4] = fmaf(er, v4, pv0[4]); pv0[5] = fmaf(er, v5, pv0[5]);
          pv0[6] = fmaf(er, v6, pv0[6]); pv0[7] = fmaf(er, v7, pv0[7]);
        } else {
          pv1[0] = fmaf(er, v0, pv1[0]); pv1[1] = fmaf(er, v1, pv1[1]);
          pv1[2] = fmaf(er, v2, pv1[2]); pv1[3] = fmaf(er, v3, pv1[3]);
          pv1[4] = fmaf(er, v4, pv1[4]); pv1[5] = fmaf(er, v5, pv1[5]);
          pv1[6] = fmaf(er, v6, pv1[6]); pv1[7] = fmaf(er, v7, pv1[7]);
        }
      }
    }
    // distributed reduce over 8-lane subgroups (xor 1,2,4) ...
#pragma unroll
    for (int st = 0; st < 3; ++st) {
      const int s = 1 << st;
      const int cnt = 8 >> (st + 1);
      bool hi = (r & s) != 0;
#pragma unroll
      for (int i = 0; i < cnt; ++i) {
        float a0 = hi ? pv0[i + cnt] : pv0[i];
        float b0 = hi ? pv0[i] : pv0[i + cnt];
        pv0[i] = a0 + __shfl_xor(b0, s);
        float a1 = hi ? pv1[i + cnt] : pv1[i];
        float b1 = hi ? pv1[i] : pv1[i + cnt];
        pv1[i] = a1 + __shfl_xor(b1, s);
      }
    }
    // ... then merge the two 8-lane halves; r<8 -> pv0 (ks even cols),
    // r>=8 -> pv1 (+32), each now a full 16-lane sum.
    bool h8 = (r & 8) != 0;
    float va = h8 ? pv1[0] : pv0[0];
    float vb = h8 ? pv0[0] : pv1[0];
    float ov = va + __shfl_xor(vb, 8);
    int g3 = ((r & 1) << 2) | (r & 2) | ((r & 4) >> 2);
    int col = w * 64 + (h8 ? 32 : 0) + q * 8 + g3;
    part[(size_t)blockIdx.x * 512 + col] = ov;
  }
#undef LOADC
#undef WRITEC
#undef LOADB
#undef LOADA
#undef MFMA16
#undef CHUNK
}

// ---------------- K3: softmax over T per b -> weights (output) -------------
__global__ void k_softmax(const float* __restrict__ scores, float* __restrict__ wts) {
  __shared__ float rm[4], rs[4];
  int b = blockIdx.x, tid = threadIdx.x;
  float s[8];
#pragma unroll
  for (int i = 0; i < 8; ++i) s[i] = scores[b * T_ + i * 256 + tid];
  float mx = s[0];
#pragma unroll
  for (int i = 1; i < 8; ++i) mx = fmaxf(mx, s[i]);
#pragma unroll
  for (int off = 1; off <= 32; off <<= 1) mx = fmaxf(mx, __shfl_xor(mx, off));
  if ((tid & 63) == 0) rm[tid >> 6] = mx;
  __syncthreads();
  mx = fmaxf(fmaxf(rm[0], rm[1]), fmaxf(rm[2], rm[3]));
  float ex[8], se = 0.f;
#pragma unroll
  for (int i = 0; i < 8; ++i) { ex[i] = __expf(s[i] - mx); se += ex[i]; }
#pragma unroll
  for (int off = 1; off <= 32; off <<= 1) se += __shfl_xor(se, off);
  if ((tid & 63) == 0) rs[tid >> 6] = se;
  __syncthreads();
  se = rs[0] + rs[1] + rs[2] + rs[3];
  float inv = 1.0f / se;
#pragma unroll
  for (int i = 0; i < 8; ++i) wts[b * T_ + i * 256 + tid] = ex[i] * inv;
}

// ---------------- K4: flash recombine partial contexts -> context ----------
__global__ void k_ctx_comb(const float* __restrict__ part, const float* __restrict__ mz,
                           float* __restrict__ ctx) {
  __shared__ float sM[32], sZ[32];
  int b = blockIdx.x, tid = threadIdx.x;  // 512 threads, thread = h
  if (tid < 32) {
    sM[tid] = mz[(b * 32 + tid) * 2];
    sZ[tid] = mz[(b * 32 + tid) * 2 + 1];
  }
  __syncthreads();
  float M = sM[0];
#pragma unroll
  for (int i = 1; i < 32; ++i) M = fmaxf(M, sM[i]);
  float denom = 0.f;
#pragma unroll
  for (int i = 0; i < 32; ++i) denom += sZ[i] * __expf(sM[i] - M);
  float s = 0.f;
#pragma unroll
  for (int i = 0; i < 32; ++i)
    s += part[((size_t)b * 32 + i) * 512 + tid] * __expf(sM[i] - M);
  ctx[b * 512 + tid] = s / denom;
}

extern "C" void kernel_launch(void* const* d_in, const int* in_sizes, int n_in,
                              void* d_out, int out_size, void* d_ws, size_t ws_size,
                              hipStream_t stream) {
  const float* enc  = (const float*)d_in[0];
  const float* dec  = (const float*)d_in[1];
  const float* Wenc = (const float*)d_in[2];
  const float* Wdec = (const float*)d_in[3];
  const float* V    = (const float*)d_in[4];
  float* out = (float*)d_out;
  char* ws = (char*)d_ws;

  u16* wsB      = (u16*)ws;                            // 512 KB bf16 tiled W_enc
  float* dpj    = (float*)(ws + 512 * 1024);           // 128 KB dec_proj
  float* scores = (float*)(ws + 640 * 1024);           // 512 KB scores
  float* part   = (float*)(ws + 1152 * 1024);          // 4 MB ctx partials (2048 x 512)
  float* mz     = (float*)(ws + 1152 * 1024 + 4 * 1024 * 1024);  // 16 KB (m,Z)

  float* ctx = out;            // [B,H] = 32768 floats
  float* wts = out + B_ * H_;  // [B,T] = 131072 floats

  hipLaunchKernelGGL(k_prep, dim3(640), dim3(256), 0, stream, Wenc, wsB, dec, Wdec, dpj);
  hipLaunchKernelGGL(k_scores, dim3(2048), dim3(512), 0, stream, enc, wsB, dpj, V,
                     scores, part, mz);
  hipLaunchKernelGGL(k_softmax, dim3(64), dim3(256), 0, stream, scores, wts);
  hipLaunchKernelGGL(k_ctx_comb, dim3(64), dim3(512), 0, stream, part, mz, ctx);
}

// Round 11
// 115.406 us; speedup vs baseline: 5.4244x; 5.4244x over previous
//
#include <hip/hip_runtime.h>

#define B_ 64
#define T_ 2048
#define H_ 512
#define A_ 512

typedef unsigned short u16;
typedef __attribute__((ext_vector_type(8))) short bf16x8;
typedef __attribute__((ext_vector_type(4))) float f32x4;

__device__ __forceinline__ unsigned cvtpk(float lo, float hi) {
  unsigned d;
  asm("v_cvt_pk_bf16_f32 %0, %1, %2" : "=v"(d) : "v"(lo), "v"(hi));
  return d;
}

__device__ __forceinline__ float bf2f(u16 h) {
  return __uint_as_float(((unsigned)h) << 16);
}

__device__ __forceinline__ float fast_tanh(float x) {
  // tanh(x) = 1 - 2/(exp2(x*2*log2e)+1); v_exp_f32 is exp2
  float e2;
  asm("v_exp_f32 %0, %1" : "=v"(e2) : "v"(x * 2.8853900817779268f));
  return 1.0f - 2.0f * __builtin_amdgcn_rcpf(e2 + 1.0f);
}

// Barrier that waits ONLY LDS ops: in-flight global loads survive it.
#define BAR_LDS() asm volatile("s_waitcnt lgkmcnt(0)\n\ts_barrier" ::: "memory")

// ---------------- K1: merged W_enc conversion + dec_proj -------------------
// blocks [0,128): W_enc fp32 -> bf16 fragment-tiled
//   unit idx = ks*2048 + (a>>4)*64 + q*16 + (a&15), holds W_enc[a][ks*32+q*8..+8]
// blocks [128,640): dec_proj[b][a] = dot(dec[b,:], W_dec[a,:])
__global__ void k_prep(const float* __restrict__ W, u16* __restrict__ wsB,
                       const float* __restrict__ dec, const float* __restrict__ Wd,
                       float* __restrict__ dp) {
  __shared__ float dl[H_];
  int tid = threadIdx.x;
  int bx = blockIdx.x;
  if (bx < 128) {
    int u = bx * 256 + tid;  // 32768 units
    int a = u >> 6;
    int hq = u & 63;
    int ks = hq >> 2;
    int q = hq & 3;
    const float4* src = (const float4*)(W + a * H_ + hq * 8);
    float4 x0 = src[0], x1 = src[1];
    uint4 pk;
    pk.x = cvtpk(x0.x, x0.y);
    pk.y = cvtpk(x0.z, x0.w);
    pk.z = cvtpk(x1.x, x1.y);
    pk.w = cvtpk(x1.z, x1.w);
    int dst = ks * 2048 + (a >> 4) * 64 + q * 16 + (a & 15);
    ((uint4*)wsB)[dst] = pk;
  } else {
    int e = bx - 128;        // 512 blocks
    int b = e >> 3;
    int a0 = (e & 7) * 64;
    dl[tid] = dec[b * H_ + tid];
    dl[tid + 256] = dec[b * H_ + tid + 256];
    __syncthreads();
    int al = tid >> 2, p = tid & 3;
    const float4* wr = (const float4*)(Wd + (a0 + al) * H_ + p * 128);
    const float4* dv = (const float4*)(dl + p * 128);
    float s = 0.f;
#pragma unroll 8
    for (int i = 0; i < 32; ++i) {
      float4 w4 = wr[i], d4 = dv[i];
      s += w4.x * d4.x + w4.y * d4.y + w4.z * d4.z + w4.w * d4.w;
    }
    s += __shfl_xor(s, 1);
    s += __shfl_xor(s, 2);
    if (p == 0) dp[b * H_ + a0 + al] = s;
  }
}

// ---------------- K2: fused GEMM + tanh + V-dot + local softmax + PV -------
// BM=64, BN=512, 8 waves, launch_bounds(512,4) -> 128 COMBINED regs/wave,
// 2 blocks/CU (cross-block overlap, proven R6 vs R7/R9/R10).
// KEY: acc shrunk to 4x2 frags (32 regs) by doing the wave's 4 n-frags in
// TWO passes over the LDS A-tile; the freed 32 regs fund B-frag rolling
// depth-2 (s0..s3) + depth-1 A-stage pipeline, all within the 128 cap.
// Pass 0 carries the staging pipeline (BAR_LDS, lgkm-only, chunked); pass 1
// is barrier-free. Epilogue: butterfly reductions, local softmax, PV.
// LDS unit u (16B, 8 bf16) = ks*256 + m*64 + q*16 + r
//   holds enc_bf16[row = m*16+r][cols ks*32+q*8 .. +8]
__launch_bounds__(512, 4)
__global__ void k_scores(const float* __restrict__ enc, const u16* __restrict__ wsB,
                         const float* __restrict__ dpj, const float* __restrict__ V,
                         float* __restrict__ scores, float* __restrict__ part,
                         float* __restrict__ mz) {
  __shared__ __attribute__((aligned(16))) u16 Ab[64 * 512];  // 64 KB
  __shared__ float red[8][64];
  int tid = threadIdx.x;
  int w = tid >> 6, l = tid & 63;
  int q = l >> 4, r = l & 15;
  int m0 = blockIdx.x * 64;
  int b = m0 >> 11;

  // staging decode: thread owns unit it*512+tid (it=0..7); ks = it*2+(tid>>8)
  int rem = tid & 255;
  int sm = rem >> 6, sq = (rem >> 4) & 3, sr = rem & 15;
  const float* ab = enc + (size_t)(m0 + sm * 16 + sr) * H_ + (tid >> 8) * 32 + sq * 8;

  // hoisted epilogue constants
  float vv[4], dd[4];
  const float* db = dpj + b * A_;
#pragma unroll
  for (int n = 0; n < 4; ++n) {
    int col = w * 64 + n * 16 + r;
    vv[n] = V[col];
    dd[n] = db[col];
  }

  const bf16x8* bfrag = (const bf16x8*)wsB;

#define LOADC(P, c)                                                     \
  { P##0 = *((const float4*)(ab + (2 * (c)) * 64));                     \
    P##1 = *((const float4*)(ab + (2 * (c)) * 64 + 4));                 \
    P##2 = *((const float4*)(ab + (2 * (c) + 1) * 64));                 \
    P##3 = *((const float4*)(ab + (2 * (c) + 1) * 64 + 4)); }
#define WRITEC(P, c)                                                    \
  { uint4 k0, k1;                                                       \
    k0.x = cvtpk((P##0).x, (P##0).y); k0.y = cvtpk((P##0).z, (P##0).w); \
    k0.z = cvtpk((P##1).x, (P##1).y); k0.w = cvtpk((P##1).z, (P##1).w); \
    k1.x = cvtpk((P##2).x, (P##2).y); k1.y = cvtpk((P##2).z, (P##2).w); \
    k1.z = cvtpk((P##3).x, (P##3).y); k1.w = cvtpk((P##3).z, (P##3).w); \
    ((uint4*)Ab)[(2 * (c)) * 512 + tid] = k0;                           \
    ((uint4*)Ab)[(2 * (c) + 1) * 512 + tid] = k1; }
#define LOADB2(dst, ks, nb)                                             \
  { dst[0] = bfrag[(ks) * 2048 + (w * 4 + (nb)) * 64 + l];              \
    dst[1] = bfrag[(ks) * 2048 + (w * 4 + (nb) + 1) * 64 + l]; }
#define MFMA8(af, bb)                                                   \
  { __builtin_amdgcn_s_setprio(1);                                      \
    _Pragma("unroll") for (int m = 0; m < 4; ++m)                       \
      _Pragma("unroll") for (int n = 0; n < 2; ++n)                     \
        acc[m][n] = __builtin_amdgcn_mfma_f32_16x16x32_bf16(            \
            af[m], bb[n], acc[m][n], 0, 0, 0);                          \
    __builtin_amdgcn_s_setprio(0); }
#define KSTEP2(ks, scur, spre, PF, nb)                                  \
  { if (PF) LOADB2(spre, (ks) + 2, nb)                                  \
    bf16x8 af[4];                                                       \
    _Pragma("unroll") for (int m = 0; m < 4; ++m)                       \
      af[m] = *((const bf16x8*)&Ab[((ks) * 256 + m * 64 + l) * 8]);     \
    MFMA8(af, scur) }
#define CHUNK2(c, PF3, nb)                                              \
  { KSTEP2(4 * (c), s0, s2, true, nb)                                   \
    KSTEP2(4 * (c) + 1, s1, s3, true, nb)                               \
    KSTEP2(4 * (c) + 2, s2, s0, PF3, nb)                                \
    KSTEP2(4 * (c) + 3, s3, s1, PF3, nb) }
#define ACC_SP(nb)                                                      \
  _Pragma("unroll") for (int n = 0; n < 2; ++n) {                       \
    _Pragma("unroll") for (int m = 0; m < 4; ++m)                       \
      _Pragma("unroll") for (int j = 0; j < 4; ++j)                     \
        sp[m * 4 + j] = fmaf(vv[(nb) + n],                              \
                             fast_tanh(acc[m][n][j] + dd[(nb) + n]),    \
                             sp[m * 4 + j]);                            \
  }

  f32x4 acc[4][2];
#pragma unroll
  for (int m = 0; m < 4; ++m)
#pragma unroll
    for (int n = 0; n < 2; ++n) acc[m][n] = (f32x4){0.f, 0.f, 0.f, 0.f};
  float sp[16];
#pragma unroll
  for (int i = 0; i < 16; ++i) sp[i] = 0.f;

  float4 pa0, pa1, pa2, pa3;
  bf16x8 s0[2], s1[2], s2[2], s3[2];

  // ---- PASS 0 (n-frags 0,1) with depth-1 A-stage pipeline ----
  LOADB2(s0, 0, 0)
  LOADB2(s1, 1, 0)
  LOADC(pa, 0)
  WRITEC(pa, 0)
  BAR_LDS();
  LOADC(pa, 1)
  CHUNK2(0, true, 0)
  WRITEC(pa, 1)
  BAR_LDS();
  LOADC(pa, 2)
  CHUNK2(1, true, 0)
  WRITEC(pa, 2)
  BAR_LDS();
  LOADC(pa, 3)
  CHUNK2(2, true, 0)
  WRITEC(pa, 3)
  BAR_LDS();
  CHUNK2(3, false, 0)

  ACC_SP(0)
#pragma unroll
  for (int m = 0; m < 4; ++m)
#pragma unroll
    for (int n = 0; n < 2; ++n) acc[m][n] = (f32x4){0.f, 0.f, 0.f, 0.f};

  // ---- PASS 1 (n-frags 2,3), barrier-free (tile fully staged) ----
  LOADB2(s0, 0, 2)
  LOADB2(s1, 1, 2)
  CHUNK2(0, true, 2)
  CHUNK2(1, true, 2)
  CHUNK2(2, true, 2)
  CHUNK2(3, false, 2)

  ACC_SP(2)

  // ---- butterfly reduce over the 16 col-lanes: lane r ends with full sum
  // of sp[bitrev4(r)] ----
#pragma unroll
  for (int st = 0; st < 4; ++st) {
    const int s = 1 << st;
    const int cnt = 16 >> (st + 1);
    bool hi = (r & s) != 0;
#pragma unroll
    for (int i = 0; i < cnt; ++i) {
      float a = hi ? sp[i + cnt] : sp[i];
      float bs = hi ? sp[i] : sp[i + cnt];
      sp[i] = a + __shfl_xor(bs, s);
    }
  }
  {
    int i4 = ((r & 1) << 3) | ((r & 2) << 1) | ((r & 4) >> 1) | ((r & 8) >> 3);
    BAR_LDS();  // all A-tile LDS reads of the K-passes done block-wide
    red[w][(i4 >> 2) * 16 + q * 4 + (i4 & 3)] = sp[0];
  }
  BAR_LDS();

  // ---- ALL waves: final row scores + local softmax ----
  float s_ = 0.f;
#pragma unroll
  for (int ww = 0; ww < 8; ++ww) s_ += red[ww][l];
  if (w == 0) scores[m0 + l] = s_;
  float mx = s_;
#pragma unroll
  for (int off = 1; off <= 32; off <<= 1) mx = fmaxf(mx, __shfl_xor(mx, off));
  float e = __expf(s_ - mx);
  float Z = e;
#pragma unroll
  for (int off = 1; off <= 32; off <<= 1) Z += __shfl_xor(Z, off);
  if (tid == 0) {
    mz[blockIdx.x * 2] = mx;
    mz[blockIdx.x * 2 + 1] = Z;
  }
  float em[4];
#pragma unroll
  for (int m = 0; m < 4; ++m) em[m] = __shfl(e, m * 16 + r);

  // ---- PV: partial ctx[col] = sum_rows e_row * enc_bf16[row][col] ----
  // wave w covers ks = 2w, 2w+1 (cols w*64 .. w*64+64).
  {
    float pv0[8], pv1[8];
#pragma unroll
    for (int j = 0; j < 8; ++j) { pv0[j] = 0.f; pv1[j] = 0.f; }
#pragma unroll
    for (int ksl = 0; ksl < 2; ++ksl) {
      int ks_ = 2 * w + ksl;
#pragma unroll
      for (int m = 0; m < 4; ++m) {
        uint4 pk = ((const uint4*)Ab)[ks_ * 256 + m * 64 + l];
        float er = em[m];
        float v0 = bf2f((u16)(pk.x & 0xffff)), v1 = bf2f((u16)(pk.x >> 16));
        float v2 = bf2f((u16)(pk.y & 0xffff)), v3 = bf2f((u16)(pk.y >> 16));
        float v4 = bf2f((u16)(pk.z & 0xffff)), v5 = bf2f((u16)(pk.z >> 16));
        float v6 = bf2f((u16)(pk.w & 0xffff)), v7 = bf2f((u16)(pk.w >> 16));
        if (ksl == 0) {
          pv0[0] = fmaf(er, v0, pv0[0]); pv0[1] = fmaf(er, v1, pv0[1]);
          pv0[2] = fmaf(er, v2, pv0[2]); pv0[3] = fmaf(er, v3, pv0[3]);
          pv0[4] = fmaf(er, v4, pv0[4]); pv0[5] = fmaf(er, v5, pv0[5]);
          pv0[6] = fmaf(er, v6, pv0[6]); pv0[7] = fmaf(er, v7, pv0[7]);
        } else {
          pv1[0] = fmaf(er, v0, pv1[0]); pv1[1] = fmaf(er, v1, pv1[1]);
          pv1[2] = fmaf(er, v2, pv1[2]); pv1[3] = fmaf(er, v3, pv1[3]);
          pv1[4] = fmaf(er, v4, pv1[4]); pv1[5] = fmaf(er, v5, pv1[5]);
          pv1[6] = fmaf(er, v6, pv1[6]); pv1[7] = fmaf(er, v7, pv1[7]);
        }
      }
    }
    // distributed reduce over 8-lane subgroups (xor 1,2,4) ...
#pragma unroll
    for (int st = 0; st < 3; ++st) {
      const int s = 1 << st;
      const int cnt = 8 >> (st + 1);
      bool hi = (r & s) != 0;
#pragma unroll
      for (int i = 0; i < cnt; ++i) {
        float a0 = hi ? pv0[i + cnt] : pv0[i];
        float b0 = hi ? pv0[i] : pv0[i + cnt];
        pv0[i] = a0 + __shfl_xor(b0, s);
        float a1 = hi ? pv1[i + cnt] : pv1[i];
        float b1 = hi ? pv1[i] : pv1[i + cnt];
        pv1[i] = a1 + __shfl_xor(b1, s);
      }
    }
    // ... then merge the two 8-lane halves; r<8 -> pv0 (ks even cols),
    // r>=8 -> pv1 (+32), each now a full 16-lane sum.
    bool h8 = (r & 8) != 0;
    float va = h8 ? pv1[0] : pv0[0];
    float vb = h8 ? pv0[0] : pv1[0];
    float ov = va + __shfl_xor(vb, 8);
    int g3 = ((r & 1) << 2) | (r & 2) | ((r & 4) >> 2);
    int col = w * 64 + (h8 ? 32 : 0) + q * 8 + g3;
    part[(size_t)blockIdx.x * 512 + col] = ov;
  }
#undef LOADC
#undef WRITEC
#undef LOADB2
#undef MFMA8
#undef KSTEP2
#undef CHUNK2
#undef ACC_SP
}

// ---------------- K3: softmax over T per b -> weights (output) -------------
__global__ void k_softmax(const float* __restrict__ scores, float* __restrict__ wts) {
  __shared__ float rm[4], rs[4];
  int b = blockIdx.x, tid = threadIdx.x;
  float s[8];
#pragma unroll
  for (int i = 0; i < 8; ++i) s[i] = scores[b * T_ + i * 256 + tid];
  float mx = s[0];
#pragma unroll
  for (int i = 1; i < 8; ++i) mx = fmaxf(mx, s[i]);
#pragma unroll
  for (int off = 1; off <= 32; off <<= 1) mx = fmaxf(mx, __shfl_xor(mx, off));
  if ((tid & 63) == 0) rm[tid >> 6] = mx;
  __syncthreads();
  mx = fmaxf(fmaxf(rm[0], rm[1]), fmaxf(rm[2], rm[3]));
  float ex[8], se = 0.f;
#pragma unroll
  for (int i = 0; i < 8; ++i) { ex[i] = __expf(s[i] - mx); se += ex[i]; }
#pragma unroll
  for (int off = 1; off <= 32; off <<= 1) se += __shfl_xor(se, off);
  if ((tid & 63) == 0) rs[tid >> 6] = se;
  __syncthreads();
  se = rs[0] + rs[1] + rs[2] + rs[3];
  float inv = 1.0f / se;
#pragma unroll
  for (int i = 0; i < 8; ++i) wts[b * T_ + i * 256 + tid] = ex[i] * inv;
}

// ---------------- K4: flash recombine partial contexts -> context ----------
__global__ void k_ctx_comb(const float* __restrict__ part, const float* __restrict__ mz,
                           float* __restrict__ ctx) {
  __shared__ float sM[32], sZ[32];
  int b = blockIdx.x, tid = threadIdx.x;  // 512 threads, thread = h
  if (tid < 32) {
    sM[tid] = mz[(b * 32 + tid) * 2];
    sZ[tid] = mz[(b * 32 + tid) * 2 + 1];
  }
  __syncthreads();
  float M = sM[0];
#pragma unroll
  for (int i = 1; i < 32; ++i) M = fmaxf(M, sM[i]);
  float denom = 0.f;
#pragma unroll
  for (int i = 0; i < 32; ++i) denom += sZ[i] * __expf(sM[i] - M);
  float s = 0.f;
#pragma unroll
  for (int i = 0; i < 32; ++i)
    s += part[((size_t)b * 32 + i) * 512 + tid] * __expf(sM[i] - M);
  ctx[b * 512 + tid] = s / denom;
}

extern "C" void kernel_launch(void* const* d_in, const int* in_sizes, int n_in,
                              void* d_out, int out_size, void* d_ws, size_t ws_size,
                              hipStream_t stream) {
  const float* enc  = (const float*)d_in[0];
  const float* dec  = (const float*)d_in[1];
  const float* Wenc = (const float*)d_in[2];
  const float* Wdec = (const float*)d_in[3];
  const float* V    = (const float*)d_in[4];
  float* out = (float*)d_out;
  char* ws = (char*)d_ws;

  u16* wsB      = (u16*)ws;                            // 512 KB bf16 tiled W_enc
  float* dpj    = (float*)(ws + 512 * 1024);           // 128 KB dec_proj
  float* scores = (float*)(ws + 640 * 1024);           // 512 KB scores
  float* part   = (float*)(ws + 1152 * 1024);          // 4 MB ctx partials (2048 x 512)
  float* mz     = (float*)(ws + 1152 * 1024 + 4 * 1024 * 1024);  // 16 KB (m,Z)

  float* ctx = out;            // [B,H] = 32768 floats
  float* wts = out + B_ * H_;  // [B,T] = 131072 floats

  hipLaunchKernelGGL(k_prep, dim3(640), dim3(256), 0, stream, Wenc, wsB, dec, Wdec, dpj);
  hipLaunchKernelGGL(k_scores, dim3(2048), dim3(512), 0, stream, enc, wsB, dpj, V,
                     scores, part, mz);
  hipLaunchKernelGGL(k_softmax, dim3(64), dim3(256), 0, stream, scores, wts);
  hipLaunchKernelGGL(k_ctx_comb, dim3(64), dim3(512), 0, stream, part, mz, ctx);
}